// Round 3
// baseline (756.507 us; speedup 1.0000x reference)
//
#include <hip/hip_runtime.h>
#include <hip/hip_bf16.h>
#include <math.h>

#define T_TOK 4096
#define H_DIM 2048
#define NH 16
#define NKV 8
#define HD 128
#define QS (NH * HD)        // 2048
#define KVS (NKV * HD)      // 1024
#define QKV_W (QS + 2*KVS)  // 4096
#define SCALE 0.08838834764831845f
// SCALE * log2(e): Q pre-scaled so softmax runs in exp2 domain with no per-elem mul
#define QSCALE (0.08838834764831845f * 1.4426950408889634f)
#define EPS 1e-6f

typedef short short8 __attribute__((ext_vector_type(8)));
typedef float floatx4 __attribute__((ext_vector_type(4)));
typedef unsigned short ushort4v __attribute__((ext_vector_type(4)));

#if __has_builtin(__builtin_amdgcn_exp2f)
#define EXP2(x) __builtin_amdgcn_exp2f(x)
#else
#define EXP2(x) exp2f(x)
#endif

__device__ __forceinline__ unsigned short f2bf(float f) {
    unsigned int u = __float_as_uint(f);
    unsigned int r = (u + 0x7FFFu + ((u >> 16) & 1u)) >> 16;   // RNE
    return (unsigned short)r;
}
__device__ __forceinline__ float bf2f(unsigned short u) {
    unsigned int v = ((unsigned int)u) << 16;
    return __uint_as_float(v);
}

// async global->LDS 16B: LDS dest is wave-uniform base + lane*16
__device__ __forceinline__ void gload_lds16(const unsigned short* g, unsigned short* l) {
    __builtin_amdgcn_global_load_lds(
        (const __attribute__((address_space(1))) unsigned int*)(const void*)g,
        (__attribute__((address_space(3))) unsigned int*)(void*)l, 16, 0, 0);
}

// ---------------- f32 -> bf16 flat convert (exact-size launch) -------------
__global__ __launch_bounds__(256) void cvt_bf16(const float* __restrict__ in,
                                                unsigned short* __restrict__ out) {
    int idx = (blockIdx.x * 256 + threadIdx.x) * 8;
    float4 v0 = *(const float4*)&in[idx];
    float4 v1 = *(const float4*)&in[idx + 4];
    short8 t;
    t[0] = (short)f2bf(v0.x); t[1] = (short)f2bf(v0.y);
    t[2] = (short)f2bf(v0.z); t[3] = (short)f2bf(v0.w);
    t[4] = (short)f2bf(v1.x); t[5] = (short)f2bf(v1.y);
    t[6] = (short)f2bf(v1.z); t[7] = (short)f2bf(v1.w);
    *(short8*)&out[idx] = t;
}

// ------------- f32 [K][N] -> bf16 [N][K] transpose+convert -----------------
__global__ __launch_bounds__(256) void cvt_transpose(const float* __restrict__ in,
                                                     unsigned short* __restrict__ out,
                                                     int K, int N) {
    __shared__ __align__(16) unsigned short t[64][72];   // [n][k], 144B rows (16B mult)
    const int tid = threadIdx.x;
    const int n0 = blockIdx.x * 64, k0 = blockIdx.y * 64;
    const int r = tid >> 4, c4 = (tid & 15) * 4;
    #pragma unroll
    for (int i = 0; i < 4; ++i) {
        int kk = r + 16 * i;
        float4 v = *(const float4*)&in[(size_t)(k0 + kk) * N + n0 + c4];
        t[c4 + 0][kk] = f2bf(v.x); t[c4 + 1][kk] = f2bf(v.y);
        t[c4 + 2][kk] = f2bf(v.z); t[c4 + 3][kk] = f2bf(v.w);
    }
    __syncthreads();
    const int n = tid >> 2, c8 = (tid & 3) * 16;
    short8 a = *(const short8*)&t[n][c8];
    short8 b = *(const short8*)&t[n][c8 + 8];
    *(short8*)&out[(size_t)(n0 + n) * K + k0 + c8] = a;
    *(short8*)&out[(size_t)(n0 + n) * K + k0 + c8 + 8] = b;
}

// ====== m97-style bf16 GEMM: C[M,N] = A[M,K] @ Bt[N,K]^T, global_load_lds ==
// block 256 = 4 waves (2x2), tile 128x128, BK=32, LDS unpadded (lane-order).
template<bool C_BF16>
__global__ __launch_bounds__(256) void gemm_bt(const unsigned short* __restrict__ A, int lda,
                                               const unsigned short* __restrict__ Bt, int ldb,
                                               void* __restrict__ Cptr, int ldc, int K) {
    __shared__ __align__(16) unsigned short As[128 * 32];
    __shared__ __align__(16) unsigned short Bs[128 * 32];
    const int tid = threadIdx.x;
    const int wave = tid >> 6, lane = tid & 63;
    const int quad = lane >> 4, l16 = lane & 15;
    const int wm = wave >> 1, wn = wave & 1;
    const int bm = blockIdx.y * 128, bn = blockIdx.x * 128;

    floatx4 acc[4][4] = {};
    for (int k0 = 0; k0 < K; k0 += 32) {
        #pragma unroll
        for (int i = 0; i < 2; ++i) {
            int c = wave * 128 + i * 64 + lane;            // 0..511 chunk id
            int row = c >> 2, off = (c & 3) * 8;
            gload_lds16(A  + (size_t)(bm + row) * lda + k0 + off, As + (size_t)(wave * 128 + i * 64) * 8);
            gload_lds16(Bt + (size_t)(bn + row) * ldb + k0 + off, Bs + (size_t)(wave * 128 + i * 64) * 8);
        }
        __syncthreads();
        short8 a[4], b[4];
        #pragma unroll
        for (int mi = 0; mi < 4; ++mi)
            a[mi] = *(const short8*)&As[(wm * 64 + mi * 16 + l16) * 32 + quad * 8];
        #pragma unroll
        for (int ni = 0; ni < 4; ++ni)
            b[ni] = *(const short8*)&Bs[(wn * 64 + ni * 16 + l16) * 32 + quad * 8];
        #pragma unroll
        for (int mi = 0; mi < 4; ++mi)
            #pragma unroll
            for (int ni = 0; ni < 4; ++ni)
                acc[mi][ni] = __builtin_amdgcn_mfma_f32_16x16x32_bf16(a[mi], b[ni], acc[mi][ni], 0, 0, 0);
        __syncthreads();
    }
    #pragma unroll
    for (int mi = 0; mi < 4; ++mi)
        #pragma unroll
        for (int ni = 0; ni < 4; ++ni)
            #pragma unroll
            for (int r = 0; r < 4; ++r) {
                int row = bm + wm * 64 + mi * 16 + quad * 4 + r;
                int col = bn + wn * 64 + ni * 16 + l16;
                if (C_BF16)
                    ((unsigned short*)Cptr)[(size_t)row * ldc + col] = f2bf(acc[mi][ni][r]);
                else
                    ((float*)Cptr)[(size_t)row * ldc + col] = acc[mi][ni][r];
            }
}

// ============ per-head RMSNorm + RoPE; q additionally scaled by QSCALE =====
__global__ __launch_bounds__(256) void rms_rope_bf16(unsigned short* __restrict__ qkv,
                                                     const int* __restrict__ positions,
                                                     const float* __restrict__ qw,
                                                     const float* __restrict__ kw) {
    const int t = blockIdx.x;
    const int wave = threadIdx.x >> 6;
    const int lane = threadIdx.x & 63;
    const float pos = (float)positions[t];
    unsigned short* row = qkv + (size_t)t * QKV_W;
    const float inv_freq = powf(1000000.0f, -(float)lane / 64.0f);
    float sv, cv;
    sincosf(pos * inv_freq, &sv, &cv);
    for (int h = wave; h < NH + NKV; h += 4) {
        unsigned short* x = row + h * HD;
        const float* w = (h < NH) ? qw : kw;
        const float hs = (h < NH) ? QSCALE : 1.0f;
        float x1 = bf2f(x[lane]);
        float x2 = bf2f(x[lane + 64]);
        float ss = x1 * x1 + x2 * x2;
        #pragma unroll
        for (int off = 32; off > 0; off >>= 1) ss += __shfl_xor(ss, off, 64);
        float r = rsqrtf(ss * (1.0f / 128.0f) + EPS) * hs;
        float n1 = x1 * r * w[lane];
        float n2 = x2 * r * w[lane + 64];
        x[lane]      = f2bf(n1 * cv - n2 * sv);
        x[lane + 64] = f2bf(n2 * cv + n1 * sv);
    }
}

// ================= MFMA causal GQA flash attention =========================
// grid (32 qtiles, 16 heads), block 256 = 4 waves. QTILE=128 rows, 64 KV/step.
// LDS: smA = Ks[64][136] aliased with Ps[128][72]; smV = Vt[128][72]. 36.8 KB.
__global__ __launch_bounds__(256, 3) void attn_mfma(unsigned short* __restrict__ qkv) {
    __shared__ __align__(16) unsigned short smA[128 * 72];   // 18432 B (Ks needs 17408)
    __shared__ __align__(16) unsigned short smV[128 * 72];   // 18432 B
    const int h = blockIdx.y, kvh = h >> 1;
    const int qt = 31 - (int)blockIdx.x;                     // longest first
    const int tid = threadIdx.x;
    const int wave = tid >> 6, lane = tid & 63;
    const int quad = lane >> 4, l16 = lane & 15;
    const int t0 = qt * 128;
    const int wrow0 = t0 + wave * 32;

    // Q fragments in registers (pre-scaled by QSCALE in rms_rope)
    short8 qf[2][4];
    #pragma unroll
    for (int rt = 0; rt < 2; ++rt)
        #pragma unroll
        for (int ks = 0; ks < 4; ++ks) {
            int rowg = t0 + wave * 32 + rt * 16 + l16;
            qf[rt][ks] = *(const short8*)&qkv[(size_t)rowg * QKV_W + h * HD + ks * 32 + quad * 8];
        }

    float m_s[2][4], l_s[2][4];
    #pragma unroll
    for (int rt = 0; rt < 2; ++rt)
        #pragma unroll
        for (int r = 0; r < 4; ++r) { m_s[rt][r] = -1e30f; l_s[rt][r] = 0.0f; }
    floatx4 oacc[2][8] = {};

    const int vd0 = (tid >> 4) * 8, vsv = (tid & 15) * 4;

    const int nst = 2 * qt + 2;
    for (int st = 0; st < nst; ++st) {
        const int s0 = st * 64;
        // ---- stage K into smA (Ks layout [64][136])
        #pragma unroll
        for (int i = 0; i < 4; ++i) {
            int c = tid + 256 * i;
            int row = c >> 4, off = (c & 15) * 8;
            *(short8*)&smA[row * 136 + off] =
                *(const short8*)&qkv[(size_t)(s0 + row) * QKV_W + QS + kvh * HD + off];
        }
        // ---- stage V transposed into smV (Vt layout [d][s], [128][72])
        {
            short8 vv[4];
            #pragma unroll
            for (int ss = 0; ss < 4; ++ss)
                vv[ss] = *(const short8*)&qkv[(size_t)(s0 + vsv + ss) * QKV_W + QS + KVS + kvh * HD + vd0];
            #pragma unroll
            for (int dd = 0; dd < 8; ++dd) {
                ushort4v p;
                p[0] = (unsigned short)vv[0][dd]; p[1] = (unsigned short)vv[1][dd];
                p[2] = (unsigned short)vv[2][dd]; p[3] = (unsigned short)vv[3][dd];
                *(ushort4v*)&smV[(vd0 + dd) * 72 + vsv] = p;
            }
        }
        __syncthreads();   // bar1: staging visible

        const bool active = (s0 <= wrow0 + 31);
        floatx4 sacc[2][4] = {};
        if (active) {
            #pragma unroll
            for (int ks = 0; ks < 4; ++ks) {
                short8 bfr[4];
                #pragma unroll
                for (int ct = 0; ct < 4; ++ct)
                    bfr[ct] = *(const short8*)&smA[(ct * 16 + l16) * 136 + ks * 32 + quad * 8];
                #pragma unroll
                for (int rt = 0; rt < 2; ++rt)
                    #pragma unroll
                    for (int ct = 0; ct < 4; ++ct)
                        sacc[rt][ct] = __builtin_amdgcn_mfma_f32_16x16x32_bf16(qf[rt][ks], bfr[ct], sacc[rt][ct], 0, 0, 0);
            }
        }
        __syncthreads();   // bar2: all Ks reads done before Ps overwrites smA

        if (active) {
            const bool needMask = (s0 + 63 > wrow0);
            #pragma unroll
            for (int rt = 0; rt < 2; ++rt) {
                if (needMask) {
                    #pragma unroll
                    for (int ct = 0; ct < 4; ++ct)
                        #pragma unroll
                        for (int r = 0; r < 4; ++r) {
                            int sg = s0 + ct * 16 + l16;
                            int tg = t0 + wave * 32 + rt * 16 + quad * 4 + r;
                            if (sg > tg) sacc[rt][ct][r] = -1e30f;
                        }
                }
                #pragma unroll
                for (int r = 0; r < 4; ++r) {
                    float mx = fmaxf(fmaxf(sacc[rt][0][r], sacc[rt][1][r]),
                                     fmaxf(sacc[rt][2][r], sacc[rt][3][r]));
                    mx = fmaxf(mx, __shfl_xor(mx, 1, 64));
                    mx = fmaxf(mx, __shfl_xor(mx, 2, 64));
                    mx = fmaxf(mx, __shfl_xor(mx, 4, 64));
                    mx = fmaxf(mx, __shfl_xor(mx, 8, 64));
                    float mold = m_s[rt][r];
                    float mnew = fmaxf(mold, mx);
                    float alpha = EXP2(mold - mnew);
                    float lsum = 0.0f;
                    int prow = wave * 32 + rt * 16 + quad * 4 + r;
                    #pragma unroll
                    for (int ct = 0; ct < 4; ++ct) {
                        float p = EXP2(sacc[rt][ct][r] - mnew);
                        lsum += p;
                        smA[prow * 72 + ct * 16 + l16] = f2bf(p);   // Ps
                    }
                    l_s[rt][r] = l_s[rt][r] * alpha + lsum;        // lane-partial l
                    m_s[rt][r] = mnew;
                    #pragma unroll
                    for (int dct = 0; dct < 8; ++dct)
                        oacc[rt][dct][r] *= alpha;
                }
            }
            // ---- O += P V (Ps rows are wave-private; lgkm ordering suffices)
            #pragma unroll
            for (int ks2 = 0; ks2 < 2; ++ks2) {
                short8 af[2];
                #pragma unroll
                for (int rt = 0; rt < 2; ++rt)
                    af[rt] = *(const short8*)&smA[(wave * 32 + rt * 16 + l16) * 72 + ks2 * 32 + quad * 8];
                #pragma unroll
                for (int dct = 0; dct < 8; ++dct) {
                    short8 bfr = *(const short8*)&smV[(dct * 16 + l16) * 72 + ks2 * 32 + quad * 8];
                    #pragma unroll
                    for (int rt = 0; rt < 2; ++rt)
                        oacc[rt][dct] = __builtin_amdgcn_mfma_f32_16x16x32_bf16(af[rt], bfr, oacc[rt][dct], 0, 0, 0);
                }
            }
        }
        __syncthreads();   // bar3: Ps/Vt reads done before next staging
    }

    // ---- epilogue: finish deferred l reduction, normalize, store bf16
    #pragma unroll
    for (int rt = 0; rt < 2; ++rt)
        #pragma unroll
        for (int r = 0; r < 4; ++r) {
            float l = l_s[rt][r];
            l += __shfl_xor(l, 1, 64);
            l += __shfl_xor(l, 2, 64);
            l += __shfl_xor(l, 4, 64);
            l += __shfl_xor(l, 8, 64);
            float linv = 1.0f / l;
            int rowg = t0 + wave * 32 + rt * 16 + quad * 4 + r;
            #pragma unroll
            for (int dct = 0; dct < 8; ++dct)
                qkv[(size_t)rowg * QKV_W + h * HD + dct * 16 + l16] = f2bf(oacc[rt][dct][r] * linv);
        }
}

extern "C" void kernel_launch(void* const* d_in, const int* in_sizes, int n_in,
                              void* d_out, int out_size, void* d_ws, size_t ws_size,
                              hipStream_t stream) {
    const int*   positions = (const int*)d_in[0];
    const float* hidden    = (const float*)d_in[1];
    const float* w_qkv     = (const float*)d_in[2];
    const float* w_o       = (const float*)d_in[3];
    const float* q_norm_w  = (const float*)d_in[4];
    const float* k_norm_w  = (const float*)d_in[5];
    float* out = (float*)d_out;

    // ws layout (64 MB): [0,32M) qkv bf16; [32M,48M) hidden bf16 (later wo_t);
    //                    [48M,64M) wqkv_t bf16
    unsigned short* qkvb   = (unsigned short*)d_ws;
    unsigned short* h_bf   = (unsigned short*)((char*)d_ws + (size_t)(32 << 20));
    unsigned short* wqkv_t = (unsigned short*)((char*)d_ws + (size_t)(48 << 20));
    unsigned short* wo_t   = (unsigned short*)((char*)d_ws + (size_t)(32 << 20));

    // converts
    cvt_bf16<<<(T_TOK * H_DIM) / (256 * 8), 256, 0, stream>>>(hidden, h_bf);
    cvt_transpose<<<dim3(QKV_W / 64, H_DIM / 64), 256, 0, stream>>>(w_qkv, wqkv_t, H_DIM, QKV_W);
    // 1) QKV projection (bf16 out)
    gemm_bt<true><<<dim3(QKV_W / 128, T_TOK / 128), 256, 0, stream>>>(
        h_bf, H_DIM, wqkv_t, H_DIM, qkvb, QKV_W, H_DIM);
    // w_o transpose (reuses h_bf region; must follow gemm1)
    cvt_transpose<<<dim3(H_DIM / 64, QS / 64), 256, 0, stream>>>(w_o, wo_t, QS, H_DIM);
    // 2) RMSNorm + RoPE in place
    rms_rope_bf16<<<T_TOK, 256, 0, stream>>>(qkvb, positions, q_norm_w, k_norm_w);
    // 3) flash attention, writes O into q-region
    attn_mfma<<<dim3(T_TOK / 128, NH), 256, 0, stream>>>(qkvb);
    // 4) output projection (f32 out)
    gemm_bt<false><<<dim3(H_DIM / 128, T_TOK / 128), 256, 0, stream>>>(
        qkvb, QKV_W, wo_t, QS, out, H_DIM, QS);
}

// Round 4
// 443.737 us; speedup vs baseline: 1.7049x; 1.7049x over previous
//
#include <hip/hip_runtime.h>
#include <hip/hip_bf16.h>
#include <math.h>

#define T_TOK 4096
#define H_DIM 2048
#define NH 16
#define NKV 8
#define HD 128
#define QS (NH * HD)        // 2048
#define KVS (NKV * HD)      // 1024
#define QKV_W (QS + 2*KVS)  // 4096
// SCALE * log2(e): Q pre-scaled so softmax runs in exp2 domain
#define QSCALE (0.08838834764831845f * 1.4426950408889634f)
#define EPS 1e-6f

typedef short short8 __attribute__((ext_vector_type(8)));
typedef float floatx4 __attribute__((ext_vector_type(4)));

#if __has_builtin(__builtin_amdgcn_exp2f)
#define EXP2(x) __builtin_amdgcn_exp2f(x)
#else
#define EXP2(x) exp2f(x)
#endif

__device__ __forceinline__ unsigned short f2bf(float f) {
    unsigned int u = __float_as_uint(f);
    unsigned int r = (u + 0x7FFFu + ((u >> 16) & 1u)) >> 16;   // RNE
    return (unsigned short)r;
}
__device__ __forceinline__ float bf2f(unsigned short u) {
    unsigned int v = ((unsigned int)u) << 16;
    return __uint_as_float(v);
}

// async global->LDS 16B: LDS dest is wave-uniform base + lane*16
__device__ __forceinline__ void gload_lds16(const unsigned short* g, unsigned short* l) {
    __builtin_amdgcn_global_load_lds(
        (const __attribute__((address_space(1))) unsigned int*)(const void*)g,
        (__attribute__((address_space(3))) unsigned int*)(void*)l, 16, 0, 0);
}

// ---------------- f32 -> bf16 flat convert ---------------------------------
__global__ __launch_bounds__(256) void cvt_bf16(const float* __restrict__ in,
                                                unsigned short* __restrict__ out) {
    int idx = (blockIdx.x * 256 + threadIdx.x) * 8;
    float4 v0 = *(const float4*)&in[idx];
    float4 v1 = *(const float4*)&in[idx + 4];
    short8 t;
    t[0] = (short)f2bf(v0.x); t[1] = (short)f2bf(v0.y);
    t[2] = (short)f2bf(v0.z); t[3] = (short)f2bf(v0.w);
    t[4] = (short)f2bf(v1.x); t[5] = (short)f2bf(v1.y);
    t[6] = (short)f2bf(v1.z); t[7] = (short)f2bf(v1.w);
    *(short8*)&out[idx] = t;
}

// ------------- f32 [K][N] -> bf16 [N][K] transpose+convert -----------------
__global__ __launch_bounds__(256) void cvt_transpose(const float* __restrict__ in,
                                                     unsigned short* __restrict__ out,
                                                     int K, int N) {
    __shared__ __align__(16) unsigned short t[64][72];
    const int tid = threadIdx.x;
    const int n0 = blockIdx.x * 64, k0 = blockIdx.y * 64;
    const int r = tid >> 4, c4 = (tid & 15) * 4;
    #pragma unroll
    for (int i = 0; i < 4; ++i) {
        int kk = r + 16 * i;
        float4 v = *(const float4*)&in[(size_t)(k0 + kk) * N + n0 + c4];
        t[c4 + 0][kk] = f2bf(v.x); t[c4 + 1][kk] = f2bf(v.y);
        t[c4 + 2][kk] = f2bf(v.z); t[c4 + 3][kk] = f2bf(v.w);
    }
    __syncthreads();
    const int n = tid >> 2, c8 = (tid & 3) * 16;
    short8 a = *(const short8*)&t[n][c8];
    short8 b = *(const short8*)&t[n][c8 + 8];
    *(short8*)&out[(size_t)(n0 + n) * K + k0 + c8] = a;
    *(short8*)&out[(size_t)(n0 + n) * K + k0 + c8 + 8] = b;
}

// ====== m97-style bf16 GEMM: C[M,N] = A[M,K] @ Bt[N,K]^T, global_load_lds ==
template<bool C_BF16>
__global__ __launch_bounds__(256) void gemm_bt(const unsigned short* __restrict__ A, int lda,
                                               const unsigned short* __restrict__ Bt, int ldb,
                                               void* __restrict__ Cptr, int ldc, int K) {
    __shared__ __align__(16) unsigned short As[128 * 32];
    __shared__ __align__(16) unsigned short Bs[128 * 32];
    const int tid = threadIdx.x;
    const int wave = tid >> 6, lane = tid & 63;
    const int quad = lane >> 4, l16 = lane & 15;
    const int wm = wave >> 1, wn = wave & 1;
    const int bm = blockIdx.y * 128, bn = blockIdx.x * 128;

    floatx4 acc[4][4] = {};
    for (int k0 = 0; k0 < K; k0 += 32) {
        #pragma unroll
        for (int i = 0; i < 2; ++i) {
            int c = wave * 128 + i * 64 + lane;
            int row = c >> 2, off = (c & 3) * 8;
            gload_lds16(A  + (size_t)(bm + row) * lda + k0 + off, As + (size_t)(wave * 128 + i * 64) * 8);
            gload_lds16(Bt + (size_t)(bn + row) * ldb + k0 + off, Bs + (size_t)(wave * 128 + i * 64) * 8);
        }
        __syncthreads();
        short8 a[4], b[4];
        #pragma unroll
        for (int mi = 0; mi < 4; ++mi)
            a[mi] = *(const short8*)&As[(wm * 64 + mi * 16 + l16) * 32 + quad * 8];
        #pragma unroll
        for (int ni = 0; ni < 4; ++ni)
            b[ni] = *(const short8*)&Bs[(wn * 64 + ni * 16 + l16) * 32 + quad * 8];
        #pragma unroll
        for (int mi = 0; mi < 4; ++mi)
            #pragma unroll
            for (int ni = 0; ni < 4; ++ni)
                acc[mi][ni] = __builtin_amdgcn_mfma_f32_16x16x32_bf16(a[mi], b[ni], acc[mi][ni], 0, 0, 0);
        __syncthreads();
    }
    #pragma unroll
    for (int mi = 0; mi < 4; ++mi)
        #pragma unroll
        for (int ni = 0; ni < 4; ++ni)
            #pragma unroll
            for (int r = 0; r < 4; ++r) {
                int row = bm + wm * 64 + mi * 16 + quad * 4 + r;
                int col = bn + wn * 64 + ni * 16 + l16;
                if (C_BF16)
                    ((unsigned short*)Cptr)[(size_t)row * ldc + col] = f2bf(acc[mi][ni][r]);
                else
                    ((float*)Cptr)[(size_t)row * ldc + col] = acc[mi][ni][r];
            }
}

// ============ per-head RMSNorm + RoPE; q additionally scaled by QSCALE =====
__global__ __launch_bounds__(256) void rms_rope_bf16(unsigned short* __restrict__ qkv,
                                                     const int* __restrict__ positions,
                                                     const float* __restrict__ qw,
                                                     const float* __restrict__ kw) {
    const int t = blockIdx.x;
    const int wave = threadIdx.x >> 6;
    const int lane = threadIdx.x & 63;
    const float pos = (float)positions[t];
    unsigned short* row = qkv + (size_t)t * QKV_W;
    const float inv_freq = powf(1000000.0f, -(float)lane / 64.0f);
    float sv, cv;
    sincosf(pos * inv_freq, &sv, &cv);
    for (int h = wave; h < NH + NKV; h += 4) {
        unsigned short* x = row + h * HD;
        const float* w = (h < NH) ? qw : kw;
        const float hs = (h < NH) ? QSCALE : 1.0f;
        float x1 = bf2f(x[lane]);
        float x2 = bf2f(x[lane + 64]);
        float ss = x1 * x1 + x2 * x2;
        #pragma unroll
        for (int off = 32; off > 0; off >>= 1) ss += __shfl_xor(ss, off, 64);
        float r = rsqrtf(ss * (1.0f / 128.0f) + EPS) * hs;
        float n1 = x1 * r * w[lane];
        float n2 = x2 * r * w[lane + 64];
        x[lane]      = f2bf(n1 * cv - n2 * sv);
        x[lane + 64] = f2bf(n2 * cv + n1 * sv);
    }
}

// ====== KV pre-pack: per kvh, per 64-token tile, contiguous 16 KB tiles ====
// Kp[kvh][tile][s][128 d, chunks swizzled c^=s&7]
// Vp[kvh][tile][d][ 64 s, chunks swizzled c^=d&7]  (V transposed)
__global__ __launch_bounds__(256) void kv_pack(const unsigned short* __restrict__ qkv,
                                               unsigned short* __restrict__ Kp,
                                               unsigned short* __restrict__ Vp) {
    const int st = blockIdx.x, kvh = blockIdx.y, tid = threadIdx.x;
    const int t0 = st * 64;
    const size_t tb = (size_t)(kvh * 64 + st) << 13;   // tile base (8192 elem)
    // ---- K: swizzle chunks within each row
    #pragma unroll
    for (int i = 0; i < 4; ++i) {
        int cid = i * 256 + tid;
        int s = cid >> 4, c = cid & 15;
        short8 v = *(const short8*)&qkv[(size_t)(t0 + s) * QKV_W + QS + kvh * HD + c * 8];
        *(short8*)&Kp[tb + s * 128 + (c ^ (s & 7)) * 8] = v;
    }
    // ---- V: transpose via LDS, then swizzled rows
    __shared__ __align__(16) unsigned short Lt[128 * 72];
    #pragma unroll
    for (int i = 0; i < 4; ++i) {
        int cid = i * 256 + tid;
        int s = cid >> 4, c = cid & 15;
        short8 v = *(const short8*)&qkv[(size_t)(t0 + s) * QKV_W + QS + KVS + kvh * HD + c * 8];
        #pragma unroll
        for (int e = 0; e < 8; ++e)
            Lt[(c * 8 + e) * 72 + s] = (unsigned short)v[e];
    }
    __syncthreads();
    #pragma unroll
    for (int i = 0; i < 4; ++i) {
        int cid = i * 256 + tid;
        int d = cid >> 3, c = cid & 7;
        short8 v = *(const short8*)&Lt[d * 72 + c * 8];
        *(short8*)&Vp[tb + d * 64 + (c ^ (d & 7)) * 8] = v;
    }
}

// ================= MFMA causal GQA flash attention =========================
// grid 512: h = bx&15 (XCD = h%8 -> KV L2 locality), qt = 31-(bx>>4).
// block 256 = 4 waves; 128 q-rows/block, 64 kv/step; no-max exp2 softmax.
// LDS: Ks[64][128] swz, Vs[128][64] swz, Ps[128][72]. 50.4 KB, 2 blocks/CU.
__global__ __launch_bounds__(256, 2) void attn_mfma(unsigned short* __restrict__ qkv,
                                                    const unsigned short* __restrict__ Kp,
                                                    const unsigned short* __restrict__ Vp) {
    __shared__ __align__(16) unsigned short Ks[64 * 128];
    __shared__ __align__(16) unsigned short Vs[128 * 64];
    __shared__ __align__(16) unsigned short Ps[128 * 72];
    const int bx = blockIdx.x;
    const int h = bx & 15, kvh = h >> 1;
    const int qt = 31 - (bx >> 4);                 // longest first
    const int tid = threadIdx.x;
    const int wave = tid >> 6, lane = tid & 63;
    const int quad = lane >> 4, l16 = lane & 15;
    const int t0 = qt * 128;
    const int wrow0 = t0 + wave * 32;
    const int swz = (l16 & 7);

    // Q fragments in registers (pre-scaled by QSCALE in rms_rope)
    short8 qf[2][4];
    #pragma unroll
    for (int rt = 0; rt < 2; ++rt)
        #pragma unroll
        for (int ks = 0; ks < 4; ++ks) {
            int rowg = t0 + wave * 32 + rt * 16 + l16;
            qf[rt][ks] = *(const short8*)&qkv[(size_t)rowg * QKV_W + h * HD + ks * 32 + quad * 8];
        }

    float l_s[2][4] = {};
    floatx4 oacc[2][8] = {};

    const int nst = 2 * qt + 2;
    for (int st = 0; st < nst; ++st) {
        const int s0 = st * 64;
        // ---- stage K/V tiles: pure async DMA, zero VALU repack
        const unsigned short* kb = Kp + (((size_t)(kvh * 64 + st)) << 13);
        const unsigned short* vb = Vp + (((size_t)(kvh * 64 + st)) << 13);
        #pragma unroll
        for (int i = 0; i < 4; ++i) {
            int ch = i * 256 + tid;
            gload_lds16(kb + (size_t)ch * 8, Ks + (i * 256 + wave * 64) * 8);
            gload_lds16(vb + (size_t)ch * 8, Vs + (i * 256 + wave * 64) * 8);
        }
        __syncthreads();   // bar1: staging visible (drains vmcnt)

        const bool active = (s0 <= wrow0 + 31);
        if (active) {
            // ---- S = Q K^T (32 MFMA / wave), swizzled conflict-free reads
            floatx4 sacc[2][4] = {};
            #pragma unroll
            for (int ks = 0; ks < 4; ++ks) {
                short8 bfr[4];
                #pragma unroll
                for (int ct = 0; ct < 4; ++ct)
                    bfr[ct] = *(const short8*)&Ks[(ct * 16 + l16) * 128 + ((ks * 4 + quad) ^ swz) * 8];
                #pragma unroll
                for (int rt = 0; rt < 2; ++rt)
                    #pragma unroll
                    for (int ct = 0; ct < 4; ++ct)
                        sacc[rt][ct] = __builtin_amdgcn_mfma_f32_16x16x32_bf16(qf[rt][ks], bfr[ct], sacc[rt][ct], 0, 0, 0);
            }
            // ---- no-max softmax: p = exp2(s) (Q pre-scaled), mask on diag
            const bool needMask = (s0 + 63 > wrow0);
            #pragma unroll
            for (int rt = 0; rt < 2; ++rt)
                #pragma unroll
                for (int r = 0; r < 4; ++r) {
                    int prow = wave * 32 + rt * 16 + quad * 4 + r;
                    float lsum = 0.0f;
                    #pragma unroll
                    for (int ct = 0; ct < 4; ++ct) {
                        float s = sacc[rt][ct][r];
                        if (needMask && (s0 + ct * 16 + l16 > t0 + prow)) s = -1e30f;
                        float p = EXP2(s);
                        lsum += p;
                        Ps[prow * 72 + ct * 16 + l16] = f2bf(p);
                    }
                    l_s[rt][r] += lsum;   // lane-partial; reduced in epilogue
                }
            // ---- O += P V (32 MFMA / wave); Ps rows wave-private, no barrier
            #pragma unroll
            for (int ks2 = 0; ks2 < 2; ++ks2) {
                short8 af[2];
                #pragma unroll
                for (int rt = 0; rt < 2; ++rt)
                    af[rt] = *(const short8*)&Ps[(wave * 32 + rt * 16 + l16) * 72 + ks2 * 32 + quad * 8];
                #pragma unroll
                for (int dct = 0; dct < 8; ++dct) {
                    short8 bfr = *(const short8*)&Vs[(dct * 16 + l16) * 64 + ((ks2 * 4 + quad) ^ swz) * 8];
                    #pragma unroll
                    for (int rt = 0; rt < 2; ++rt)
                        oacc[rt][dct] = __builtin_amdgcn_mfma_f32_16x16x32_bf16(af[rt], bfr, oacc[rt][dct], 0, 0, 0);
                }
            }
        }
        __syncthreads();   // bar2: Ks/Vs reads done before next staging
    }

    // ---- epilogue: reduce l across the 16 col-lanes, normalize, store bf16
    #pragma unroll
    for (int rt = 0; rt < 2; ++rt)
        #pragma unroll
        for (int r = 0; r < 4; ++r) {
            float l = l_s[rt][r];
            l += __shfl_xor(l, 1, 64);
            l += __shfl_xor(l, 2, 64);
            l += __shfl_xor(l, 4, 64);
            l += __shfl_xor(l, 8, 64);
            float linv = 1.0f / l;
            int rowg = t0 + wave * 32 + rt * 16 + quad * 4 + r;
            #pragma unroll
            for (int dct = 0; dct < 8; ++dct)
                qkv[(size_t)rowg * QKV_W + h * HD + dct * 16 + l16] = f2bf(oacc[rt][dct][r] * linv);
        }
}

extern "C" void kernel_launch(void* const* d_in, const int* in_sizes, int n_in,
                              void* d_out, int out_size, void* d_ws, size_t ws_size,
                              hipStream_t stream) {
    const int*   positions = (const int*)d_in[0];
    const float* hidden    = (const float*)d_in[1];
    const float* w_qkv     = (const float*)d_in[2];
    const float* w_o       = (const float*)d_in[3];
    const float* q_norm_w  = (const float*)d_in[4];
    const float* k_norm_w  = (const float*)d_in[5];
    float* out = (float*)d_out;

    // ws layout (64 MB):
    //   [0,32M)  qkvb bf16
    //   [32,48M) h_bf (GEMM1)  -> then Kp [32,40M) + Vp [40,48M)
    //   [48,64M) wqkv_t (GEMM1) -> then wo_t [48,56M)
    unsigned short* qkvb   = (unsigned short*)d_ws;
    unsigned short* h_bf   = (unsigned short*)((char*)d_ws + ((size_t)32 << 20));
    unsigned short* Kp     = (unsigned short*)((char*)d_ws + ((size_t)32 << 20));
    unsigned short* Vp     = (unsigned short*)((char*)d_ws + ((size_t)40 << 20));
    unsigned short* wqkv_t = (unsigned short*)((char*)d_ws + ((size_t)48 << 20));
    unsigned short* wo_t   = (unsigned short*)((char*)d_ws + ((size_t)48 << 20));

    cvt_bf16<<<(T_TOK * H_DIM) / (256 * 8), 256, 0, stream>>>(hidden, h_bf);
    cvt_transpose<<<dim3(QKV_W / 64, H_DIM / 64), 256, 0, stream>>>(w_qkv, wqkv_t, H_DIM, QKV_W);
    // 1) QKV projection (bf16 out)
    gemm_bt<true><<<dim3(QKV_W / 128, T_TOK / 128), 256, 0, stream>>>(
        h_bf, H_DIM, wqkv_t, H_DIM, qkvb, QKV_W, H_DIM);
    // 2) RMSNorm + RoPE in place
    rms_rope_bf16<<<T_TOK, 256, 0, stream>>>(qkvb, positions, q_norm_w, k_norm_w);
    // 3) pack K (post-RoPE) and V^T into swizzled contiguous tiles
    kv_pack<<<dim3(T_TOK / 64, NKV), 256, 0, stream>>>(qkvb, Kp, Vp);
    // w_o transpose (overwrites wqkv_t region; safe after gemm1)
    cvt_transpose<<<dim3(H_DIM / 64, QS / 64), 256, 0, stream>>>(w_o, wo_t, QS, H_DIM);
    // 4) flash attention, writes O into q-region of qkvb
    attn_mfma<<<512, 256, 0, stream>>>(qkvb, Kp, Vp);
    // 5) output projection (f32 out)
    gemm_bt<false><<<dim3(H_DIM / 128, T_TOK / 128), 256, 0, stream>>>(
        qkvb, QKV_W, wo_t, QS, out, H_DIM, QS);
}

// Round 5
// 438.190 us; speedup vs baseline: 1.7264x; 1.0127x over previous
//
#include <hip/hip_runtime.h>
#include <hip/hip_bf16.h>
#include <math.h>

#define T_TOK 4096
#define H_DIM 2048
#define NH 16
#define NKV 8
#define HD 128
#define QS (NH * HD)        // 2048
#define KVS (NKV * HD)      // 1024
#define QKV_W (QS + 2*KVS)  // 4096
// SCALE * log2(e): Q pre-scaled so softmax runs in exp2 domain
#define QSCALE (0.08838834764831845f * 1.4426950408889634f)
#define EPS 1e-6f

typedef short short8 __attribute__((ext_vector_type(8)));
typedef short short4v __attribute__((ext_vector_type(4)));
typedef float floatx4 __attribute__((ext_vector_type(4)));

#if __has_builtin(__builtin_amdgcn_exp2f)
#define EXP2(x) __builtin_amdgcn_exp2f(x)
#else
#define EXP2(x) exp2f(x)
#endif

__device__ __forceinline__ unsigned short f2bf(float f) {
    unsigned int u = __float_as_uint(f);
    unsigned int r = (u + 0x7FFFu + ((u >> 16) & 1u)) >> 16;   // RNE
    return (unsigned short)r;
}
__device__ __forceinline__ float bf2f(unsigned short u) {
    unsigned int v = ((unsigned int)u) << 16;
    return __uint_as_float(v);
}
// packed f32x2 -> bf16x2 (v_cvt_pk_bf16_f32 on gfx950)
__device__ __forceinline__ unsigned int pk2(float a, float b) {
    union { __hip_bfloat162 h; unsigned int u; } c;
    c.h = __float22bfloat162_rn(make_float2(a, b));
    return c.u;
}

// async global->LDS 16B: LDS dest is wave-uniform base + lane*16
__device__ __forceinline__ void gload_lds16(const unsigned short* g, unsigned short* l) {
    __builtin_amdgcn_global_load_lds(
        (const __attribute__((address_space(1))) unsigned int*)(const void*)g,
        (__attribute__((address_space(3))) unsigned int*)(void*)l, 16, 0, 0);
}

// ---------------- f32 -> bf16 flat convert ---------------------------------
__global__ __launch_bounds__(256) void cvt_bf16(const float* __restrict__ in,
                                                unsigned short* __restrict__ out) {
    int idx = (blockIdx.x * 256 + threadIdx.x) * 8;
    float4 v0 = *(const float4*)&in[idx];
    float4 v1 = *(const float4*)&in[idx + 4];
    short8 t;
    t[0] = (short)f2bf(v0.x); t[1] = (short)f2bf(v0.y);
    t[2] = (short)f2bf(v0.z); t[3] = (short)f2bf(v0.w);
    t[4] = (short)f2bf(v1.x); t[5] = (short)f2bf(v1.y);
    t[6] = (short)f2bf(v1.z); t[7] = (short)f2bf(v1.w);
    *(short8*)&out[idx] = t;
}

// ------------- f32 [K][N] -> bf16 [N][K] transpose+convert -----------------
__global__ __launch_bounds__(256) void cvt_transpose(const float* __restrict__ in,
                                                     unsigned short* __restrict__ out,
                                                     int K, int N) {
    __shared__ __align__(16) unsigned short t[64][72];
    const int tid = threadIdx.x;
    const int n0 = blockIdx.x * 64, k0 = blockIdx.y * 64;
    const int r = tid >> 4, c4 = (tid & 15) * 4;
    #pragma unroll
    for (int i = 0; i < 4; ++i) {
        int kk = r + 16 * i;
        float4 v = *(const float4*)&in[(size_t)(k0 + kk) * N + n0 + c4];
        t[c4 + 0][kk] = f2bf(v.x); t[c4 + 1][kk] = f2bf(v.y);
        t[c4 + 2][kk] = f2bf(v.z); t[c4 + 3][kk] = f2bf(v.w);
    }
    __syncthreads();
    const int n = tid >> 2, c8 = (tid & 3) * 16;
    short8 a = *(const short8*)&t[n][c8];
    short8 b = *(const short8*)&t[n][c8 + 8];
    *(short8*)&out[(size_t)(n0 + n) * K + k0 + c8] = a;
    *(short8*)&out[(size_t)(n0 + n) * K + k0 + c8 + 8] = b;
}

// ====== m97-style bf16 GEMM: C[M,N] = A[M,K] @ Bt[N,K]^T, global_load_lds ==
template<bool C_BF16>
__global__ __launch_bounds__(256) void gemm_bt(const unsigned short* __restrict__ A, int lda,
                                               const unsigned short* __restrict__ Bt, int ldb,
                                               void* __restrict__ Cptr, int ldc, int K) {
    __shared__ __align__(16) unsigned short As[128 * 32];
    __shared__ __align__(16) unsigned short Bs[128 * 32];
    const int tid = threadIdx.x;
    const int wave = tid >> 6, lane = tid & 63;
    const int quad = lane >> 4, l16 = lane & 15;
    const int wm = wave >> 1, wn = wave & 1;
    const int bm = blockIdx.y * 128, bn = blockIdx.x * 128;

    floatx4 acc[4][4] = {};
    for (int k0 = 0; k0 < K; k0 += 32) {
        #pragma unroll
        for (int i = 0; i < 2; ++i) {
            int c = wave * 128 + i * 64 + lane;
            int row = c >> 2, off = (c & 3) * 8;
            gload_lds16(A  + (size_t)(bm + row) * lda + k0 + off, As + (size_t)(wave * 128 + i * 64) * 8);
            gload_lds16(Bt + (size_t)(bn + row) * ldb + k0 + off, Bs + (size_t)(wave * 128 + i * 64) * 8);
        }
        __syncthreads();
        short8 a[4], b[4];
        #pragma unroll
        for (int mi = 0; mi < 4; ++mi)
            a[mi] = *(const short8*)&As[(wm * 64 + mi * 16 + l16) * 32 + quad * 8];
        #pragma unroll
        for (int ni = 0; ni < 4; ++ni)
            b[ni] = *(const short8*)&Bs[(wn * 64 + ni * 16 + l16) * 32 + quad * 8];
        #pragma unroll
        for (int mi = 0; mi < 4; ++mi)
            #pragma unroll
            for (int ni = 0; ni < 4; ++ni)
                acc[mi][ni] = __builtin_amdgcn_mfma_f32_16x16x32_bf16(a[mi], b[ni], acc[mi][ni], 0, 0, 0);
        __syncthreads();
    }
    #pragma unroll
    for (int mi = 0; mi < 4; ++mi)
        #pragma unroll
        for (int ni = 0; ni < 4; ++ni)
            #pragma unroll
            for (int r = 0; r < 4; ++r) {
                int row = bm + wm * 64 + mi * 16 + quad * 4 + r;
                int col = bn + wn * 64 + ni * 16 + l16;
                if (C_BF16)
                    ((unsigned short*)Cptr)[(size_t)row * ldc + col] = f2bf(acc[mi][ni][r]);
                else
                    ((float*)Cptr)[(size_t)row * ldc + col] = acc[mi][ni][r];
            }
}

// ============ per-head RMSNorm + RoPE; q additionally scaled by QSCALE =====
__global__ __launch_bounds__(256) void rms_rope_bf16(unsigned short* __restrict__ qkv,
                                                     const int* __restrict__ positions,
                                                     const float* __restrict__ qw,
                                                     const float* __restrict__ kw) {
    const int t = blockIdx.x;
    const int wave = threadIdx.x >> 6;
    const int lane = threadIdx.x & 63;
    const float pos = (float)positions[t];
    unsigned short* row = qkv + (size_t)t * QKV_W;
    const float inv_freq = powf(1000000.0f, -(float)lane / 64.0f);
    float sv, cv;
    sincosf(pos * inv_freq, &sv, &cv);
    for (int h = wave; h < NH + NKV; h += 4) {
        unsigned short* x = row + h * HD;
        const float* w = (h < NH) ? qw : kw;
        const float hs = (h < NH) ? QSCALE : 1.0f;
        float x1 = bf2f(x[lane]);
        float x2 = bf2f(x[lane + 64]);
        float ss = x1 * x1 + x2 * x2;
        #pragma unroll
        for (int off = 32; off > 0; off >>= 1) ss += __shfl_xor(ss, off, 64);
        float r = rsqrtf(ss * (1.0f / 128.0f) + EPS) * hs;
        float n1 = x1 * r * w[lane];
        float n2 = x2 * r * w[lane + 64];
        x[lane]      = f2bf(n1 * cv - n2 * sv);
        x[lane + 64] = f2bf(n2 * cv + n1 * sv);
    }
}

// ====== KV pre-pack: per kvh, per 64-token tile, contiguous 16 KB tiles ====
// Kp[kvh][tile][s][128 d, chunks swizzled c^=s&7]
// Vp[kvh][tile][d][ 64 s, chunks swizzled c^=d&7]  (V transposed)
__global__ __launch_bounds__(256) void kv_pack(const unsigned short* __restrict__ qkv,
                                               unsigned short* __restrict__ Kp,
                                               unsigned short* __restrict__ Vp) {
    const int st = blockIdx.x, kvh = blockIdx.y, tid = threadIdx.x;
    const int t0 = st * 64;
    const size_t tb = (size_t)(kvh * 64 + st) << 13;   // tile base (8192 elem)
    #pragma unroll
    for (int i = 0; i < 4; ++i) {
        int cid = i * 256 + tid;
        int s = cid >> 4, c = cid & 15;
        short8 v = *(const short8*)&qkv[(size_t)(t0 + s) * QKV_W + QS + kvh * HD + c * 8];
        *(short8*)&Kp[tb + s * 128 + (c ^ (s & 7)) * 8] = v;
    }
    __shared__ __align__(16) unsigned short Lt[128 * 72];
    #pragma unroll
    for (int i = 0; i < 4; ++i) {
        int cid = i * 256 + tid;
        int s = cid >> 4, c = cid & 15;
        short8 v = *(const short8*)&qkv[(size_t)(t0 + s) * QKV_W + QS + KVS + kvh * HD + c * 8];
        #pragma unroll
        for (int e = 0; e < 8; ++e)
            Lt[(c * 8 + e) * 72 + s] = (unsigned short)v[e];
    }
    __syncthreads();
    #pragma unroll
    for (int i = 0; i < 4; ++i) {
        int cid = i * 256 + tid;
        int d = cid >> 3, c = cid & 7;
        short8 v = *(const short8*)&Lt[d * 72 + c * 8];
        *(short8*)&Vp[tb + d * 64 + (c ^ (d & 7)) * 8] = v;
    }
}

// ================= MFMA causal GQA flash attention =========================
// Transposed-S scheme: S^T = K·Q^T via operand swap; P converts to the PV
// A-fragment in-register (C-frag (s=quad*4+r, t=l16) == A-frag (m=l16,
// k=quad*4+j) of a K=16 MFMA). No P LDS round-trip. LDS = Ks+Vs = 32 KB.
// Balanced schedule: co-resident blocks (c, c+256) get qt and 31-qt.
__global__ __launch_bounds__(256, 2) void attn_mfma(unsigned short* __restrict__ qkv,
                                                    const unsigned short* __restrict__ Kp,
                                                    const unsigned short* __restrict__ Vp) {
    __shared__ __align__(16) unsigned short Ks[64 * 128];
    __shared__ __align__(16) unsigned short Vs[128 * 64];
    const int bx = blockIdx.x;
    const int h = bx & 15, kvh = h >> 1;            // XCD = bx%8 tracks h%8
    const int g = bx >> 4;                          // 0..31
    const int qt = (g < 16) ? (31 - g) : (g - 16);  // pair sums = 31
    const int tid = threadIdx.x;
    const int wave = tid >> 6, lane = tid & 63;
    const int quad = lane >> 4, l16 = lane & 15;
    const int t0 = qt * 128;
    const int wrow0 = t0 + wave * 32;
    const int swz = l16 & 7;

    // Q fragments (pre-scaled by QSCALE); used as the B-operand of K·Q^T
    short8 qf[2][4];
    #pragma unroll
    for (int rt = 0; rt < 2; ++rt)
        #pragma unroll
        for (int ks = 0; ks < 4; ++ks) {
            int rowg = t0 + wave * 32 + rt * 16 + l16;
            qf[rt][ks] = *(const short8*)&qkv[(size_t)rowg * QKV_W + h * HD + ks * 32 + quad * 8];
        }

    float l_s[2] = {};            // per-lane partial row-sum for t = l16 (+16rt)
    floatx4 oacc[2][8] = {};

    const int nst = 2 * qt + 2;
    for (int st = 0; st < nst; ++st) {
        const int s0 = st * 64;
        const unsigned short* kb = Kp + (((size_t)(kvh * 64 + st)) << 13);
        const unsigned short* vb = Vp + (((size_t)(kvh * 64 + st)) << 13);
        #pragma unroll
        for (int i = 0; i < 4; ++i) {
            int ch = i * 256 + tid;
            gload_lds16(kb + (size_t)ch * 8, Ks + (i * 256 + wave * 64) * 8);
            gload_lds16(vb + (size_t)ch * 8, Vs + (i * 256 + wave * 64) * 8);
        }
        __syncthreads();   // bar1: staging visible

        const bool active = (s0 <= wrow0 + 31);
        if (active) {
            // ---- S^T = K Q^T: C[s=quad*4+r (+16ct)][t=l16 (+16rt)]
            floatx4 sacc[2][4] = {};
            #pragma unroll
            for (int ks = 0; ks < 4; ++ks) {
                short8 kfr[4];
                #pragma unroll
                for (int ct = 0; ct < 4; ++ct)
                    kfr[ct] = *(const short8*)&Ks[(ct * 16 + l16) * 128 + ((ks * 4 + quad) ^ swz) * 8];
                #pragma unroll
                for (int rt = 0; rt < 2; ++rt)
                    #pragma unroll
                    for (int ct = 0; ct < 4; ++ct)
                        sacc[rt][ct] = __builtin_amdgcn_mfma_f32_16x16x32_bf16(kfr[ct], qf[rt][ks], sacc[rt][ct], 0, 0, 0);
            }
            // ---- no-max softmax on S^T; pack P into PV A-fragments
            const bool needMask = (s0 + 63 > wrow0);
            short4v pp[2][4];
            #pragma unroll
            for (int rt = 0; rt < 2; ++rt) {
                const int tg = t0 + wave * 32 + rt * 16 + l16;
                float lsum = 0.0f;
                #pragma unroll
                for (int ct = 0; ct < 4; ++ct) {
                    float p[4];
                    #pragma unroll
                    for (int r = 0; r < 4; ++r) {
                        float s = sacc[rt][ct][r];
                        if (needMask && (s0 + ct * 16 + quad * 4 + r > tg)) s = -1e30f;
                        p[r] = EXP2(s);
                        lsum += p[r];
                    }
                    union { short4v s4; unsigned int u[2]; } pk;
                    pk.u[0] = pk2(p[0], p[1]);
                    pk.u[1] = pk2(p[2], p[3]);
                    pp[rt][ct] = pk.s4;
                }
                l_s[rt] += lsum;
            }
            // ---- O += P V : A = pp (m=l16 -> t, k=quad*4+j -> s), B from Vs
            #pragma unroll
            for (int ct = 0; ct < 4; ++ct) {
                const int sb = ct * 16 + quad * 4;
                const int ph0 = (((sb >> 3) ^ swz) << 3) | (sb & 7);
#if __has_builtin(__builtin_amdgcn_mfma_f32_16x16x16bf16_1k)
                #pragma unroll
                for (int dct = 0; dct < 8; ++dct) {
                    short4v bfr = *(const short4v*)&Vs[(dct * 16 + l16) * 64 + ph0];
                    #pragma unroll
                    for (int rt = 0; rt < 2; ++rt)
                        oacc[rt][dct] = __builtin_amdgcn_mfma_f32_16x16x16bf16_1k(pp[rt][ct], bfr, oacc[rt][dct], 0, 0, 0);
                }
#else
                // zero-padded 16x16x32 fallback (upper-k A lanes are zero)
                const int sb1 = sb + 4;
                const int ph1 = (((sb1 >> 3) ^ swz) << 3) | (sb1 & 7);
                short8 ap[2];
                #pragma unroll
                for (int rt = 0; rt < 2; ++rt) {
                    union { short8 s8; short4v s4[2]; } a;
                    a.s4[0] = pp[rt][ct];
                    a.s4[1] = short4v{0, 0, 0, 0};
                    ap[rt] = a.s8;
                }
                #pragma unroll
                for (int dct = 0; dct < 8; ++dct) {
                    union { short8 s8; short4v s4[2]; } b;
                    b.s4[0] = *(const short4v*)&Vs[(dct * 16 + l16) * 64 + ph0];
                    b.s4[1] = *(const short4v*)&Vs[(dct * 16 + l16) * 64 + ph1];
                    #pragma unroll
                    for (int rt = 0; rt < 2; ++rt)
                        oacc[rt][dct] = __builtin_amdgcn_mfma_f32_16x16x32_bf16(ap[rt], b.s8, oacc[rt][dct], 0, 0, 0);
                }
#endif
            }
        }
        __syncthreads();   // bar2: Ks/Vs reads done before next staging
    }

    // ---- epilogue: reduce l across quads, redistribute, normalize, store
    float lred[2];
    #pragma unroll
    for (int rt = 0; rt < 2; ++rt) {
        float l = l_s[rt];
        l += __shfl_xor(l, 16, 64);
        l += __shfl_xor(l, 32, 64);
        lred[rt] = l;                 // valid for t = l16 (+rt*16) in all quads
    }
    #pragma unroll
    for (int rt = 0; rt < 2; ++rt)
        #pragma unroll
        for (int r = 0; r < 4; ++r) {
            float l = __shfl(lred[rt], quad * 4 + r, 64);   // l for t = quad*4+r
            float linv = 1.0f / l;
            int rowg = t0 + wave * 32 + rt * 16 + quad * 4 + r;
            #pragma unroll
            for (int dct = 0; dct < 8; ++dct)
                qkv[(size_t)rowg * QKV_W + h * HD + dct * 16 + l16] = f2bf(oacc[rt][dct][r] * linv);
        }
}

extern "C" void kernel_launch(void* const* d_in, const int* in_sizes, int n_in,
                              void* d_out, int out_size, void* d_ws, size_t ws_size,
                              hipStream_t stream) {
    const int*   positions = (const int*)d_in[0];
    const float* hidden    = (const float*)d_in[1];
    const float* w_qkv     = (const float*)d_in[2];
    const float* w_o       = (const float*)d_in[3];
    const float* q_norm_w  = (const float*)d_in[4];
    const float* k_norm_w  = (const float*)d_in[5];
    float* out = (float*)d_out;

    unsigned short* qkvb   = (unsigned short*)d_ws;
    unsigned short* h_bf   = (unsigned short*)((char*)d_ws + ((size_t)32 << 20));
    unsigned short* Kp     = (unsigned short*)((char*)d_ws + ((size_t)32 << 20));
    unsigned short* Vp     = (unsigned short*)((char*)d_ws + ((size_t)40 << 20));
    unsigned short* wqkv_t = (unsigned short*)((char*)d_ws + ((size_t)48 << 20));
    unsigned short* wo_t   = (unsigned short*)((char*)d_ws + ((size_t)48 << 20));

    cvt_bf16<<<(T_TOK * H_DIM) / (256 * 8), 256, 0, stream>>>(hidden, h_bf);
    cvt_transpose<<<dim3(QKV_W / 64, H_DIM / 64), 256, 0, stream>>>(w_qkv, wqkv_t, H_DIM, QKV_W);
    gemm_bt<true><<<dim3(QKV_W / 128, T_TOK / 128), 256, 0, stream>>>(
        h_bf, H_DIM, wqkv_t, H_DIM, qkvb, QKV_W, H_DIM);
    rms_rope_bf16<<<T_TOK, 256, 0, stream>>>(qkvb, positions, q_norm_w, k_norm_w);
    kv_pack<<<dim3(T_TOK / 64, NKV), 256, 0, stream>>>(qkvb, Kp, Vp);
    cvt_transpose<<<dim3(H_DIM / 64, QS / 64), 256, 0, stream>>>(w_o, wo_t, QS, H_DIM);
    attn_mfma<<<512, 256, 0, stream>>>(qkvb, Kp, Vp);
    gemm_bt<false><<<dim3(H_DIM / 128, T_TOK / 128), 256, 0, stream>>>(
        qkvb, QKV_W, wo_t, QS, out, H_DIM, QS);
}

// Round 6
// 412.119 us; speedup vs baseline: 1.8357x; 1.0633x over previous
//
#include <hip/hip_runtime.h>
#include <hip/hip_bf16.h>
#include <math.h>

#define T_TOK 4096
#define H_DIM 2048
#define NH 16
#define NKV 8
#define HD 128
#define QS (NH * HD)        // 2048
#define KVS (NKV * HD)      // 1024
#define QKV_W (QS + 2*KVS)  // 4096
// SCALE * log2(e): Q pre-scaled so softmax runs in exp2 domain
#define QSCALE (0.08838834764831845f * 1.4426950408889634f)
#define EPS 1e-6f

typedef short short8 __attribute__((ext_vector_type(8)));
typedef short short4v __attribute__((ext_vector_type(4)));
typedef float floatx4 __attribute__((ext_vector_type(4)));

#if __has_builtin(__builtin_amdgcn_exp2f)
#define EXP2(x) __builtin_amdgcn_exp2f(x)
#else
#define EXP2(x) exp2f(x)
#endif

__device__ __forceinline__ unsigned short f2bf(float f) {
    unsigned int u = __float_as_uint(f);
    unsigned int r = (u + 0x7FFFu + ((u >> 16) & 1u)) >> 16;   // RNE
    return (unsigned short)r;
}
__device__ __forceinline__ float bf2f(unsigned short u) {
    unsigned int v = ((unsigned int)u) << 16;
    return __uint_as_float(v);
}
// packed f32x2 -> bf16x2
__device__ __forceinline__ unsigned int pk2(float a, float b) {
    union { __hip_bfloat162 h; unsigned int u; } c;
    c.h = __float22bfloat162_rn(make_float2(a, b));
    return c.u;
}

// async global->LDS 16B: LDS dest is wave-uniform base + lane*16
__device__ __forceinline__ void gload_lds16(const unsigned short* g, unsigned short* l) {
    __builtin_amdgcn_global_load_lds(
        (const __attribute__((address_space(1))) unsigned int*)(const void*)g,
        (__attribute__((address_space(3))) unsigned int*)(void*)l, 16, 0, 0);
}

// ---------------- f32 -> bf16 flat convert ---------------------------------
__global__ __launch_bounds__(256) void cvt_bf16(const float* __restrict__ in,
                                                unsigned short* __restrict__ out) {
    int idx = (blockIdx.x * 256 + threadIdx.x) * 8;
    float4 v0 = *(const float4*)&in[idx];
    float4 v1 = *(const float4*)&in[idx + 4];
    short8 t;
    t[0] = (short)f2bf(v0.x); t[1] = (short)f2bf(v0.y);
    t[2] = (short)f2bf(v0.z); t[3] = (short)f2bf(v0.w);
    t[4] = (short)f2bf(v1.x); t[5] = (short)f2bf(v1.y);
    t[6] = (short)f2bf(v1.z); t[7] = (short)f2bf(v1.w);
    *(short8*)&out[idx] = t;
}

// ------------- f32 [K][N] -> bf16 [N][K] transpose+convert -----------------
__global__ __launch_bounds__(256) void cvt_transpose(const float* __restrict__ in,
                                                     unsigned short* __restrict__ out,
                                                     int K, int N) {
    __shared__ __align__(16) unsigned short t[64][72];
    const int tid = threadIdx.x;
    const int n0 = blockIdx.x * 64, k0 = blockIdx.y * 64;
    const int r = tid >> 4, c4 = (tid & 15) * 4;
    #pragma unroll
    for (int i = 0; i < 4; ++i) {
        int kk = r + 16 * i;
        float4 v = *(const float4*)&in[(size_t)(k0 + kk) * N + n0 + c4];
        t[c4 + 0][kk] = f2bf(v.x); t[c4 + 1][kk] = f2bf(v.y);
        t[c4 + 2][kk] = f2bf(v.z); t[c4 + 3][kk] = f2bf(v.w);
    }
    __syncthreads();
    const int n = tid >> 2, c8 = (tid & 3) * 16;
    short8 a = *(const short8*)&t[n][c8];
    short8 b = *(const short8*)&t[n][c8 + 8];
    *(short8*)&out[(size_t)(n0 + n) * K + k0 + c8] = a;
    *(short8*)&out[(size_t)(n0 + n) * K + k0 + c8 + 8] = b;
}

// ====== m97-style bf16 GEMM: C[M,N] = A[M,K] @ Bt[N,K]^T, global_load_lds ==
template<bool C_BF16>
__global__ __launch_bounds__(256) void gemm_bt(const unsigned short* __restrict__ A, int lda,
                                               const unsigned short* __restrict__ Bt, int ldb,
                                               void* __restrict__ Cptr, int ldc, int K) {
    __shared__ __align__(16) unsigned short As[128 * 32];
    __shared__ __align__(16) unsigned short Bs[128 * 32];
    const int tid = threadIdx.x;
    const int wave = tid >> 6, lane = tid & 63;
    const int quad = lane >> 4, l16 = lane & 15;
    const int wm = wave >> 1, wn = wave & 1;
    const int bm = blockIdx.y * 128, bn = blockIdx.x * 128;

    floatx4 acc[4][4] = {};
    for (int k0 = 0; k0 < K; k0 += 32) {
        #pragma unroll
        for (int i = 0; i < 2; ++i) {
            int c = wave * 128 + i * 64 + lane;
            int row = c >> 2, off = (c & 3) * 8;
            gload_lds16(A  + (size_t)(bm + row) * lda + k0 + off, As + (size_t)(wave * 128 + i * 64) * 8);
            gload_lds16(Bt + (size_t)(bn + row) * ldb + k0 + off, Bs + (size_t)(wave * 128 + i * 64) * 8);
        }
        __syncthreads();
        short8 a[4], b[4];
        #pragma unroll
        for (int mi = 0; mi < 4; ++mi)
            a[mi] = *(const short8*)&As[(wm * 64 + mi * 16 + l16) * 32 + quad * 8];
        #pragma unroll
        for (int ni = 0; ni < 4; ++ni)
            b[ni] = *(const short8*)&Bs[(wn * 64 + ni * 16 + l16) * 32 + quad * 8];
        #pragma unroll
        for (int mi = 0; mi < 4; ++mi)
            #pragma unroll
            for (int ni = 0; ni < 4; ++ni)
                acc[mi][ni] = __builtin_amdgcn_mfma_f32_16x16x32_bf16(a[mi], b[ni], acc[mi][ni], 0, 0, 0);
        __syncthreads();
    }
    #pragma unroll
    for (int mi = 0; mi < 4; ++mi)
        #pragma unroll
        for (int ni = 0; ni < 4; ++ni)
            #pragma unroll
            for (int r = 0; r < 4; ++r) {
                int row = bm + wm * 64 + mi * 16 + quad * 4 + r;
                int col = bn + wn * 64 + ni * 16 + l16;
                if (C_BF16)
                    ((unsigned short*)Cptr)[(size_t)row * ldc + col] = f2bf(acc[mi][ni][r]);
                else
                    ((float*)Cptr)[(size_t)row * ldc + col] = acc[mi][ni][r];
            }
}

// ============ per-head RMSNorm + RoPE; q additionally scaled by QSCALE =====
__global__ __launch_bounds__(256) void rms_rope_bf16(unsigned short* __restrict__ qkv,
                                                     const int* __restrict__ positions,
                                                     const float* __restrict__ qw,
                                                     const float* __restrict__ kw) {
    const int t = blockIdx.x;
    const int wave = threadIdx.x >> 6;
    const int lane = threadIdx.x & 63;
    const float pos = (float)positions[t];
    unsigned short* row = qkv + (size_t)t * QKV_W;
    const float inv_freq = powf(1000000.0f, -(float)lane / 64.0f);
    float sv, cv;
    sincosf(pos * inv_freq, &sv, &cv);
    for (int h = wave; h < NH + NKV; h += 4) {
        unsigned short* x = row + h * HD;
        const float* w = (h < NH) ? qw : kw;
        const float hs = (h < NH) ? QSCALE : 1.0f;
        float x1 = bf2f(x[lane]);
        float x2 = bf2f(x[lane + 64]);
        float ss = x1 * x1 + x2 * x2;
        #pragma unroll
        for (int off = 32; off > 0; off >>= 1) ss += __shfl_xor(ss, off, 64);
        float r = rsqrtf(ss * (1.0f / 128.0f) + EPS) * hs;
        float n1 = x1 * r * w[lane];
        float n2 = x2 * r * w[lane + 64];
        x[lane]      = f2bf(n1 * cv - n2 * sv);
        x[lane + 64] = f2bf(n2 * cv + n1 * sv);
    }
}

// ====== KV pre-pack: per kvh, per 128-token tile, contiguous 32 KB tiles ===
// Kp tile: chunk (s, c) -> slot s*16 + (c ^ (s&7))           [s=token, c=dim/8]
// Vp tile: V^T chunk (d, cs) -> slot d*16 + (cs ^ (d&7)); within-chunk halves
//          (2x 4 tokens) swapped iff (d>>3)&1  -> conflict-free b64 reads
__global__ __launch_bounds__(256) void kv_pack(const unsigned short* __restrict__ qkv,
                                               unsigned short* __restrict__ Kp,
                                               unsigned short* __restrict__ Vp) {
    const int tile = blockIdx.x, kvh = blockIdx.y, tid = threadIdx.x;
    const int t0 = tile * 128;
    const size_t tb = (size_t)(kvh * 32 + tile) * 16384;
    // ---- K: swizzle chunks within each row
    #pragma unroll
    for (int i = 0; i < 8; ++i) {
        int cid = i * 256 + tid;
        int s = cid >> 4, c = cid & 15;
        short8 v = *(const short8*)&qkv[(size_t)(t0 + s) * QKV_W + QS + kvh * HD + c * 8];
        *(short8*)&Kp[tb + (s * 16 + (c ^ (s & 7))) * 8] = v;
    }
    // ---- V: transpose via LDS
    __shared__ __align__(16) unsigned short Lt[128 * 136];
    #pragma unroll
    for (int i = 0; i < 8; ++i) {
        int cid = i * 256 + tid;
        int s = cid >> 4, c = cid & 15;
        short8 v = *(const short8*)&qkv[(size_t)(t0 + s) * QKV_W + QS + KVS + kvh * HD + c * 8];
        #pragma unroll
        for (int e = 0; e < 8; ++e)
            Lt[(c * 8 + e) * 136 + s] = (unsigned short)v[e];
    }
    __syncthreads();
    #pragma unroll
    for (int i = 0; i < 8; ++i) {
        int cid = i * 256 + tid;
        int d = cid >> 4, cs = cid & 15;
        short8 v = *(const short8*)&Lt[d * 136 + cs * 8];
        short8 w;
        if ((d >> 3) & 1) {
            #pragma unroll
            for (int e = 0; e < 8; ++e) w[e] = v[e ^ 4];   // swap 4-token halves
        } else w = v;
        *(short8*)&Vp[tb + (d * 16 + (cs ^ (d & 7))) * 8] = w;
    }
}

// ================= MFMA causal GQA flash attention =========================
// Transposed-S scheme (S^T = K·Q^T); 128 q-rows/block, 128 kv/step.
// ct-interleaved: per 16-col block do QK^T -> exp2/pack -> PV immediately.
// LDS Ks+Vs = 64 KB -> 2 blocks/CU. Balanced pairing: blocks (c, c+256)
// get qt and 31-qt.
__global__ __launch_bounds__(256, 2) void attn_mfma(unsigned short* __restrict__ qkv,
                                                    const unsigned short* __restrict__ Kp,
                                                    const unsigned short* __restrict__ Vp) {
    __shared__ __align__(16) unsigned short Ks[128 * 128];
    __shared__ __align__(16) unsigned short Vs[128 * 128];
    const int bx = blockIdx.x;
    const int h = bx & 15, kvh = h >> 1;            // XCD = bx%8 tracks h%8
    const int g = bx >> 4;                          // 0..31
    const int qt = (g < 16) ? (31 - g) : (g - 16);  // pair sums = 31
    const int tid = threadIdx.x;
    const int wave = tid >> 6, lane = tid & 63;
    const int quad = lane >> 4, l16 = lane & 15;
    const int t0 = qt * 128;
    const int wrow0 = t0 + wave * 32;
    const int swz = l16 & 7;
    const int hsel = (l16 >> 3) & 1;                // V half-swap selector
    const int vhalf = ((quad & 1) ^ hsel) * 4;
    const int q2 = quad >> 1;

    // Q fragments (pre-scaled by QSCALE); B-operand of K·Q^T
    short8 qf[2][4];
    #pragma unroll
    for (int rt = 0; rt < 2; ++rt)
        #pragma unroll
        for (int ks = 0; ks < 4; ++ks) {
            int rowg = t0 + wave * 32 + rt * 16 + l16;
            qf[rt][ks] = *(const short8*)&qkv[(size_t)rowg * QKV_W + h * HD + ks * 32 + quad * 8];
        }

    float l_s[2] = {};
    floatx4 oacc[2][8] = {};

    for (int st = 0; st <= qt; ++st) {
        const int s0 = st * 128;
        const unsigned short* kb = Kp + (size_t)(kvh * 32 + st) * 16384;
        const unsigned short* vb = Vp + (size_t)(kvh * 32 + st) * 16384;
        #pragma unroll
        for (int i = 0; i < 8; ++i) {
            int ch = i * 256 + tid;
            gload_lds16(kb + (size_t)ch * 8, Ks + (i * 256 + wave * 64) * 8);
        }
        #pragma unroll
        for (int i = 0; i < 8; ++i) {
            int ch = i * 256 + tid;
            gload_lds16(vb + (size_t)ch * 8, Vs + (i * 256 + wave * 64) * 8);
        }
        __syncthreads();   // bar1: staging visible

        const bool diag = (st == qt);
        #pragma unroll
        for (int ct = 0; ct < 8; ++ct) {
            const int smin = s0 + ct * 16;
            if (diag && smin > wrow0 + 31) continue;   // wave-uniform causal skip
            // ---- S^T block: C[s=quad*4+r][t=l16 (+16rt)]
            floatx4 sacc[2] = {};
            #pragma unroll
            for (int ks = 0; ks < 4; ++ks) {
                short8 kfr = *(const short8*)&Ks[(ct * 16 + l16) * 128 + ((ks * 4 + quad) ^ swz) * 8];
                sacc[0] = __builtin_amdgcn_mfma_f32_16x16x32_bf16(kfr, qf[0][ks], sacc[0], 0, 0, 0);
                sacc[1] = __builtin_amdgcn_mfma_f32_16x16x32_bf16(kfr, qf[1][ks], sacc[1], 0, 0, 0);
            }
            // ---- exp2 + pack into PV A-fragments
            short4v pp[2];
            #pragma unroll
            for (int rt = 0; rt < 2; ++rt) {
                const int tg = wrow0 + rt * 16 + l16;
                float p[4];
                float lsum = 0.0f;
                #pragma unroll
                for (int r = 0; r < 4; ++r) {
                    float s = sacc[rt][r];
                    if (diag && (smin + quad * 4 + r > tg)) s = -1e30f;
                    p[r] = EXP2(s);
                    lsum += p[r];
                }
                l_s[rt] += lsum;
                union { short4v s4; unsigned int u[2]; } pk;
                pk.u[0] = pk2(p[0], p[1]);
                pk.u[1] = pk2(p[2], p[3]);
                pp[rt] = pk.s4;
            }
            // ---- O += P V  (K=16 MFMA; conflict-free b64 V reads)
            const int vc = (((ct * 2 + q2) ^ swz)) * 8 + vhalf;
#if __has_builtin(__builtin_amdgcn_mfma_f32_16x16x16bf16_1k)
            #pragma unroll
            for (int dct = 0; dct < 8; ++dct) {
                short4v bfr = *(const short4v*)&Vs[(dct * 16 + l16) * 128 + vc];
                oacc[0][dct] = __builtin_amdgcn_mfma_f32_16x16x16bf16_1k(pp[0], bfr, oacc[0][dct], 0, 0, 0);
                oacc[1][dct] = __builtin_amdgcn_mfma_f32_16x16x16bf16_1k(pp[1], bfr, oacc[1][dct], 0, 0, 0);
            }
#else
            #pragma unroll
            for (int dct = 0; dct < 8; ++dct) {
                union { short8 s8; short4v s4[2]; } b;
                b.s4[0] = *(const short4v*)&Vs[(dct * 16 + l16) * 128 + vc];
                b.s4[1] = short4v{0, 0, 0, 0};
                #pragma unroll
                for (int rt = 0; rt < 2; ++rt) {
                    union { short8 s8; short4v s4[2]; } a;
                    a.s4[0] = pp[rt];
                    a.s4[1] = short4v{0, 0, 0, 0};
                    oacc[rt][dct] = __builtin_amdgcn_mfma_f32_16x16x32_bf16(a.s8, b.s8, oacc[rt][dct], 0, 0, 0);
                }
            }
#endif
        }
        __syncthreads();   // bar2: Ks/Vs reads done before next staging
    }

    // ---- epilogue: reduce l across quads, redistribute, normalize, store
    float lred[2];
    #pragma unroll
    for (int rt = 0; rt < 2; ++rt) {
        float l = l_s[rt];
        l += __shfl_xor(l, 16, 64);
        l += __shfl_xor(l, 32, 64);
        lred[rt] = l;                 // valid for t = l16 (+rt*16) in all quads
    }
    #pragma unroll
    for (int rt = 0; rt < 2; ++rt)
        #pragma unroll
        for (int r = 0; r < 4; ++r) {
            float l = __shfl(lred[rt], quad * 4 + r, 64);
            float linv = 1.0f / l;
            int rowg = t0 + wave * 32 + rt * 16 + quad * 4 + r;
            #pragma unroll
            for (int dct = 0; dct < 8; ++dct)
                qkv[(size_t)rowg * QKV_W + h * HD + dct * 16 + l16] = f2bf(oacc[rt][dct][r] * linv);
        }
}

extern "C" void kernel_launch(void* const* d_in, const int* in_sizes, int n_in,
                              void* d_out, int out_size, void* d_ws, size_t ws_size,
                              hipStream_t stream) {
    const int*   positions = (const int*)d_in[0];
    const float* hidden    = (const float*)d_in[1];
    const float* w_qkv     = (const float*)d_in[2];
    const float* w_o       = (const float*)d_in[3];
    const float* q_norm_w  = (const float*)d_in[4];
    const float* k_norm_w  = (const float*)d_in[5];
    float* out = (float*)d_out;

    unsigned short* qkvb   = (unsigned short*)d_ws;
    unsigned short* h_bf   = (unsigned short*)((char*)d_ws + ((size_t)32 << 20));
    unsigned short* Kp     = (unsigned short*)((char*)d_ws + ((size_t)32 << 20));
    unsigned short* Vp     = (unsigned short*)((char*)d_ws + ((size_t)40 << 20));
    unsigned short* wqkv_t = (unsigned short*)((char*)d_ws + ((size_t)48 << 20));
    unsigned short* wo_t   = (unsigned short*)((char*)d_ws + ((size_t)48 << 20));

    cvt_bf16<<<(T_TOK * H_DIM) / (256 * 8), 256, 0, stream>>>(hidden, h_bf);
    cvt_transpose<<<dim3(QKV_W / 64, H_DIM / 64), 256, 0, stream>>>(w_qkv, wqkv_t, H_DIM, QKV_W);
    gemm_bt<true><<<dim3(QKV_W / 128, T_TOK / 128), 256, 0, stream>>>(
        h_bf, H_DIM, wqkv_t, H_DIM, qkvb, QKV_W, H_DIM);
    rms_rope_bf16<<<T_TOK, 256, 0, stream>>>(qkvb, positions, q_norm_w, k_norm_w);
    kv_pack<<<dim3(T_TOK / 128, NKV), 256, 0, stream>>>(qkvb, Kp, Vp);
    cvt_transpose<<<dim3(H_DIM / 64, QS / 64), 256, 0, stream>>>(w_o, wo_t, QS, H_DIM);
    attn_mfma<<<512, 256, 0, stream>>>(qkvb, Kp, Vp);
    gemm_bt<false><<<dim3(H_DIM / 128, T_TOK / 128), 256, 0, stream>>>(
        qkvb, QKV_W, wo_t, QS, out, H_DIM, QS);
}